// Round 3
// baseline (283.042 us; speedup 1.0000x reference)
//
#include <hip/hip_runtime.h>

#define N_RAYS   65536
#define N_SAMPLES 128
#define RPT      8                      // rays per tile (per block iteration)
#define GRID     768                    // 3 blocks/CU x 256 CU, all resident
#define NTG      (N_RAYS / RPT)         // 8192 tile-groups
#define MAXT     ((NTG + GRID - 1) / GRID)  // 11 tiles max per block
#define TILE_F   (RPT * N_SAMPLES * 3)  // 3072 floats: grad OR color for one tile

// async global->LDS, 16B per lane. LDS dest is wave-uniform base + lane*16;
// global src is per-lane.
__device__ __forceinline__ void gll16(const float* g, float* l) {
    __builtin_amdgcn_global_load_lds(
        (const __attribute__((address_space(1))) void*)g,
        (__attribute__((address_space(3))) void*)l,
        16, 0, 0);
}

__device__ __forceinline__ float sigmoidf(float x) {
    return 1.0f / (1.0f + __expf(-x));
}

// stage one tile's grad+color into buffer b (wave-private chunks, no barrier)
// exactly 6 vmem instructions.
__device__ __forceinline__ void stage(const float* __restrict__ grad,
                                      const float* __restrict__ color,
                                      float* b, int wv, int l64, size_t rayb) {
    const float* g = grad  + rayb * (N_SAMPLES * 3);
    const float* c = color + rayb * (N_SAMPLES * 3);
    #pragma unroll
    for (int k = 0; k < 3; ++k) {
        const int q = wv * 3 + k;                    // wave wv owns chunks 3wv..3wv+2
        gll16(g + (size_t)q * 256 + l64 * 4, b + q * 256);
        gll16(c + (size_t)q * 256 + l64 * 4, b + TILE_F + q * 256);
    }
}

__global__ __launch_bounds__(256, 3) void neus_kernel(
    const float* __restrict__ sdf,
    const float* __restrict__ color,
    const float* __restrict__ z_vals,
    const float* __restrict__ grad_theta,
    const float* __restrict__ rays_d,
    const float* __restrict__ s_ptr,
    const float* __restrict__ car_ptr,
    float* __restrict__ out_pixel,     // [N,3]
    float* __restrict__ out_invdepth,  // [N]
    float* __restrict__ out_weight)    // [N,S]
{
    // double buffer: each buf holds [grad TILE_F floats][color TILE_F floats]
    // 2 * 6144 floats * 4B = 48 KiB (+ ~1 KiB lds_rd) -> 3 blocks/CU
    __shared__ __align__(16) float buf[2][TILE_F * 2];
    __shared__ float lds_rd[MAXT * RPT * 3];          // rays_d cache

    const int tid = threadIdx.x;
    const int l   = tid & 31;          // lane within ray (samples 4l..4l+3)
    const int rl  = tid >> 5;          // ray within tile (0..7)
    const int wv  = tid >> 6;          // wave (0..3)
    const int l64 = tid & 63;
    const int bid = blockIdx.x;

    const int ntiles = (NTG - bid + GRID - 1) / GRID;   // 10 or 11

    // one-time: stage this block's rays_d into LDS so the steady-state loop
    // has EXACTLY 8 vmem ops per tile (keeps the vmcnt count exact)
    const int nrd = ntiles * RPT * 3;
    for (int k = tid; k < nrd; k += 256) {
        const int it  = k / 24;
        const int rem = k - it * 24;
        lds_rd[k] = rays_d[(size_t)(bid + it * GRID) * 24 + rem];
    }

    const float sv  = s_ptr[0];
    const float car = car_ptr[0];
    const float omc = 1.0f - car;

    __syncthreads();   // drains everything; nothing pipelined yet

    // ---- prologue: tile 0 in flight (8 vmem ops) ----
    size_t tg = bid;
    int parity = 0;
    stage(grad_theta, color, buf[0], wv, l64, tg * RPT);
    float4 sdP = *(const float4*)(sdf    + (tg * RPT + rl) * N_SAMPLES + 4 * l);
    float4 zzP = *(const float4*)(z_vals + (tg * RPT + rl) * N_SAMPLES + 4 * l);

    for (int i = 0; ; ++i) {
        const size_t tg_next = tg + GRID;
        const bool   more    = (i + 1) < ntiles;       // block-uniform
        float4 sdN, zzN;
        if (more) {
            // issue tile i+1 (8 counted vmem: 6 gll16 + 2 dwordx4), then wait
            // ONLY until <=8 outstanding: tile i's loads retired, tile i+1's
            // stay in flight across the whole compute phase (T4: never 0).
            stage(grad_theta, color, buf[parity ^ 1], wv, l64, tg_next * RPT);
            sdN = *(const float4*)(sdf    + (tg_next * RPT + rl) * N_SAMPLES + 4 * l);
            zzN = *(const float4*)(z_vals + (tg_next * RPT + rl) * N_SAMPLES + 4 * l);
            asm volatile("s_waitcnt vmcnt(8)" ::: "memory");
        } else {
            asm volatile("s_waitcnt vmcnt(0)" ::: "memory");
        }

        // ---- compute tile i from buf[parity] + sdP/zzP ----
        // Read ALL staged LDS data up front, then fence: no later staging op
        // (which overwrites this buffer next iteration) can be hoisted above
        // a pending read of it (rule #18-style ordering hazard).
        const float* bb = buf[parity];
        const int fo = rl * 384 + 12 * l;              // 16B-aligned
        const float4 gA = *(const float4*)(bb + fo);
        const float4 gB = *(const float4*)(bb + fo + 4);
        const float4 gC = *(const float4*)(bb + fo + 8);
        const float4 cA = *(const float4*)(bb + TILE_F + fo);
        const float4 cB = *(const float4*)(bb + TILE_F + fo + 4);
        const float4 cC = *(const float4*)(bb + TILE_F + fo + 8);
        const float rdx = lds_rd[i * 24 + rl * 3 + 0];
        const float rdy = lds_rd[i * 24 + rl * 3 + 1];
        const float rdz = lds_rd[i * 24 + rl * 3 + 2];
        asm volatile("s_waitcnt lgkmcnt(0)" ::: "memory");

        const float tc0 = rdx * gA.x + rdy * gA.y + rdz * gA.z;
        const float tc1 = rdx * gA.w + rdy * gB.x + rdz * gB.y;
        const float tc2 = rdx * gB.z + rdy * gB.w + rdz * gC.x;
        const float tc3 = rdx * gC.y + rdy * gC.z + rdz * gC.w;

        auto iter_cos = [&](float tc) -> float {
            float a = fmaxf(fmaf(tc, -0.5f, 0.5f), 0.0f);
            float b = fmaxf(-tc, 0.0f);
            return -(a * omc + b * car);
        };
        const float ic0 = iter_cos(tc0);
        const float ic1 = iter_cos(tc1);
        const float ic2 = iter_cos(tc2);
        const float ic3 = iter_cos(tc3);

        const float zn = __shfl_down(zzP.x, 1, 32);    // z[4l+4]; garbage @ l=31 (unused)
        const float d0 = zzP.y - zzP.x;
        const float d1 = zzP.z - zzP.y;
        const float d2 = zzP.w - zzP.z;
        const float d3 = zn    - zzP.w;

        auto alpha_f = [&](float sdv, float ic, float d) -> float {
            float h  = ic * d * 0.5f;
            float pc = sigmoidf((sdv - h) * sv);
            float nc = sigmoidf((sdv + h) * sv);
            float a  = (pc - nc + 1e-5f) / (pc + 1e-5f);
            return fminf(fmaxf(a, 0.0f), 1.0f);
        };
        const float a0 = alpha_f(sdP.x, ic0, d0);
        const float a1 = alpha_f(sdP.y, ic1, d1);
        const float a2 = alpha_f(sdP.z, ic2, d2);
        const float a3 = (l == 31) ? 0.0f : alpha_f(sdP.w, ic3, d3); // sample 127: zero

        const float om0 = 1.0f - a0;
        const float om1 = 1.0f - a1;
        const float om2 = 1.0f - a2;
        const float om3 = 1.0f - a3;

        // width-32 exclusive product scan (5 steps)
        float scan = om0 * om1 * om2 * om3;
        #pragma unroll
        for (int off = 1; off < 32; off <<= 1) {
            float v = __shfl_up(scan, off, 32);
            if (l >= off) scan *= v;
        }
        float excl = __shfl_up(scan, 1, 32);
        if (l == 0) excl = 1.0f;

        float t  = excl;
        const float w0 = (l == 0) ? 0.0f : t * a0;     // ref: T[0] prepended zero
        t *= om0; const float w1 = t * a1;
        t *= om1; const float w2 = t * a2;
        t *= om2; const float w3 = t * a3;             // l==31: a3==0

        float inv = w0 / zzP.x + w1 / zzP.y + w2 / zzP.z + w3 / zzP.w;

        const size_t ray  = tg * RPT + rl;
        const size_t base = ray * N_SAMPLES;
        *(float4*)(out_weight + base + 4 * l) = make_float4(w0, w1, w2, w3);

        // pixel partials (AoS: c[4l]=(A.x,A.y,A.z), c[4l+1]=(A.w,B.x,B.y),
        //                  c[4l+2]=(B.z,B.w,C.x), c[4l+3]=(C.y,C.z,C.w))
        float pr = w0 * cA.x + w1 * cA.w + w2 * cB.z + w3 * cC.y;
        float pg = w0 * cA.y + w1 * cB.x + w2 * cB.w + w3 * cC.z;
        float pb = w0 * cA.z + w1 * cB.y + w2 * cC.x + w3 * cC.w;

        #pragma unroll
        for (int off = 16; off > 0; off >>= 1) {
            pr  += __shfl_xor(pr,  off, 32);
            pg  += __shfl_xor(pg,  off, 32);
            pb  += __shfl_xor(pb,  off, 32);
            inv += __shfl_xor(inv, off, 32);
        }

        if (l == 0) {
            out_pixel[ray * 3 + 0] = pr;
            out_pixel[ray * 3 + 1] = pg;
            out_pixel[ray * 3 + 2] = pb;
            out_invdepth[ray]      = inv;
        }

        if (!more) break;
        sdP = sdN; zzP = zzN; tg = tg_next; parity ^= 1;
    }
}

extern "C" void kernel_launch(void* const* d_in, const int* in_sizes, int n_in,
                              void* d_out, int out_size, void* d_ws, size_t ws_size,
                              hipStream_t stream) {
    const float* sdf        = (const float*)d_in[0];
    const float* color      = (const float*)d_in[1];
    const float* z_vals     = (const float*)d_in[2];
    const float* grad_theta = (const float*)d_in[3];
    const float* rays_d     = (const float*)d_in[4];
    const float* s_ptr      = (const float*)d_in[5];
    const float* car_ptr    = (const float*)d_in[6];

    float* out          = (float*)d_out;
    float* out_pixel    = out;                        // N*3
    float* out_invdepth = out + (size_t)N_RAYS * 3;   // N
    float* out_weight   = out + (size_t)N_RAYS * 4;   // N*S

    dim3 block(256);
    dim3 grid(GRID);

    neus_kernel<<<grid, block, 0, stream>>>(
        sdf, color, z_vals, grad_theta, rays_d, s_ptr, car_ptr,
        out_pixel, out_invdepth, out_weight);
}

// Round 4
// 261.889 us; speedup vs baseline: 1.0808x; 1.0808x over previous
//
#include <hip/hip_runtime.h>

#define N_RAYS   65536
#define N_SAMPLES 128

typedef float f4 __attribute__((ext_vector_type(4)));

// non-temporal 16B load (nt bit -> evict-first / no-allocate hint down the
// cache hierarchy). Used ONLY for grad_theta: shrinks the cacheable working
// set to ~193MB (< 256MB Infinity Cache) so color/sdf/z/outputs stay
// L3-resident across dispatches.
__device__ __forceinline__ f4 ntload4(const float* p) {
    return __builtin_nontemporal_load((const f4*)p);
}
__device__ __forceinline__ f4 load4(const float* p) {
    return *(const f4*)p;
}

__device__ __forceinline__ float sigmoidf(float x) {
    return 1.0f / (1.0f + __expf(-x));
}

__global__ __launch_bounds__(256) void neus_kernel(
    const float* __restrict__ sdf,
    const float* __restrict__ color,
    const float* __restrict__ z_vals,
    const float* __restrict__ grad_theta,
    const float* __restrict__ rays_d,
    const float* __restrict__ s_ptr,
    const float* __restrict__ car_ptr,
    float* __restrict__ out_pixel,     // [N,3]
    float* __restrict__ out_invdepth,  // [N]
    float* __restrict__ out_weight)    // [N,S]
{
    const int tid = threadIdx.x;
    const int l   = tid & 31;          // lane within ray (owns samples 4l..4l+3)
    const int rl  = tid >> 5;          // ray within block (0..7); 2 rays/wave
    const int ray = blockIdx.x * 8 + rl;

    const size_t base = (size_t)ray * N_SAMPLES;
    const size_t b3   = base * 3 + 12 * l;   // lane's first AoS float (16B-aligned)

    // contiguous 16B/lane loads
    const f4 sd = load4(sdf    + base + 4 * l);
    const f4 zz = load4(z_vals + base + 4 * l);

    // grad: NON-TEMPORAL (96MB/dispatch, zero reuse) -> don't pollute L3
    const f4 gA = ntload4(grad_theta + b3);
    const f4 gB = ntload4(grad_theta + b3 + 4);
    const f4 gC = ntload4(grad_theta + b3 + 8);

    // color: regular (stays L3-resident across dispatches)
    const f4 cA = load4(color + b3);
    const f4 cB = load4(color + b3 + 4);
    const f4 cC = load4(color + b3 + 8);

    const float rdx = rays_d[ray * 3 + 0];
    const float rdy = rays_d[ray * 3 + 1];
    const float rdz = rays_d[ray * 3 + 2];
    const float sv  = s_ptr[0];
    const float car = car_ptr[0];
    const float omc = 1.0f - car;

    // true cosine per sample (AoS: g[4l]=(A.x,A.y,A.z), g[4l+1]=(A.w,B.x,B.y),
    //                          g[4l+2]=(B.z,B.w,C.x), g[4l+3]=(C.y,C.z,C.w))
    const float tc0 = rdx * gA.x + rdy * gA.y + rdz * gA.z;
    const float tc1 = rdx * gA.w + rdy * gB.x + rdz * gB.y;
    const float tc2 = rdx * gB.z + rdy * gB.w + rdz * gC.x;
    const float tc3 = rdx * gC.y + rdy * gC.z + rdz * gC.w;

    auto iter_cos = [&](float tc) -> float {
        float a = fmaxf(fmaf(tc, -0.5f, 0.5f), 0.0f);
        float b = fmaxf(-tc, 0.0f);
        return -(a * omc + b * car);
    };
    const float ic0 = iter_cos(tc0);
    const float ic1 = iter_cos(tc1);
    const float ic2 = iter_cos(tc2);
    const float ic3 = iter_cos(tc3);

    // dists: 3 in-register, 1 from neighbor lane (width-32 confined)
    const float zn = __shfl_down(zz.x, 1, 32);   // z[4l+4]; garbage @ l=31 (unused)
    const float d0 = zz.y - zz.x;
    const float d1 = zz.z - zz.y;
    const float d2 = zz.w - zz.z;
    const float d3 = zn   - zz.w;

    auto alpha_f = [&](float sdv, float ic, float d) -> float {
        float h  = ic * d * 0.5f;
        float pc = sigmoidf((sdv - h) * sv);
        float nc = sigmoidf((sdv + h) * sv);
        float a  = (pc - nc + 1e-5f) / (pc + 1e-5f);
        return fminf(fmaxf(a, 0.0f), 1.0f);
    };
    const float a0 = alpha_f(sd.x, ic0, d0);
    const float a1 = alpha_f(sd.y, ic1, d1);
    const float a2 = alpha_f(sd.z, ic2, d2);
    const float a3 = (l == 31) ? 0.0f : alpha_f(sd.w, ic3, d3); // sample 127: zero

    const float om0 = 1.0f - a0;
    const float om1 = 1.0f - a1;
    const float om2 = 1.0f - a2;
    const float om3 = 1.0f - a3;

    // width-32 exclusive product scan (5 steps)
    float scan = om0 * om1 * om2 * om3;
    #pragma unroll
    for (int off = 1; off < 32; off <<= 1) {
        float v = __shfl_up(scan, off, 32);
        if (l >= off) scan *= v;
    }
    float excl = __shfl_up(scan, 1, 32);
    if (l == 0) excl = 1.0f;

    // weights; ref prepends ZERO transmittance at sample 0 -> w[0]=0
    float t  = excl;
    const float w0 = (l == 0) ? 0.0f : t * a0;
    t *= om0; const float w1 = t * a1;
    t *= om1; const float w2 = t * a2;
    t *= om2; const float w3 = t * a3;   // l==31: a3==0 -> 0

    float inv = w0 / zz.x + w1 / zz.y + w2 / zz.z + w3 / zz.w;

    // contiguous 16B/lane weight store (regular: weight stays L3-resident)
    f4 wv; wv.x = w0; wv.y = w1; wv.z = w2; wv.w = w3;
    *(f4*)(out_weight + base + 4 * l) = wv;

    // pixel partials
    float pr = w0 * cA.x + w1 * cA.w + w2 * cB.z + w3 * cC.y;
    float pg = w0 * cA.y + w1 * cB.x + w2 * cB.w + w3 * cC.z;
    float pb = w0 * cA.z + w1 * cB.y + w2 * cC.x + w3 * cC.w;

    // width-32 butterfly reduction (5 steps x 4 values)
    #pragma unroll
    for (int off = 16; off > 0; off >>= 1) {
        pr  += __shfl_xor(pr,  off, 32);
        pg  += __shfl_xor(pg,  off, 32);
        pb  += __shfl_xor(pb,  off, 32);
        inv += __shfl_xor(inv, off, 32);
    }

    if (l == 0) {
        out_pixel[ray * 3 + 0] = pr;
        out_pixel[ray * 3 + 1] = pg;
        out_pixel[ray * 3 + 2] = pb;
        out_invdepth[ray]      = inv;
    }
}

extern "C" void kernel_launch(void* const* d_in, const int* in_sizes, int n_in,
                              void* d_out, int out_size, void* d_ws, size_t ws_size,
                              hipStream_t stream) {
    const float* sdf        = (const float*)d_in[0];
    const float* color      = (const float*)d_in[1];
    const float* z_vals     = (const float*)d_in[2];
    const float* grad_theta = (const float*)d_in[3];
    const float* rays_d     = (const float*)d_in[4];
    const float* s_ptr      = (const float*)d_in[5];
    const float* car_ptr    = (const float*)d_in[6];

    float* out          = (float*)d_out;
    float* out_pixel    = out;                        // N*3
    float* out_invdepth = out + (size_t)N_RAYS * 3;   // N
    float* out_weight   = out + (size_t)N_RAYS * 4;   // N*S

    dim3 block(256);                 // 4 waves = 8 rays per block
    dim3 grid(N_RAYS / 8);           // 8192 blocks

    neus_kernel<<<grid, block, 0, stream>>>(
        sdf, color, z_vals, grad_theta, rays_d, s_ptr, car_ptr,
        out_pixel, out_invdepth, out_weight);
}